// Round 2
// baseline (141.842 us; speedup 1.0000x reference)
//
#include <hip/hip_runtime.h>
#include <cstdint>

#define S_CNT 10000
#define R_CNT 10000

// 16 lanes per sample-PAIR: each group of 16 lanes handles 2 consecutive
// samples. All 10 vmem loads (2 int4 X rows + 8 float4 embedding slices)
// are issued before any use to maximize memory-level parallelism for the
// random row gathers. Two shfl_xor reduction trees, lane 0 writes float2.
__global__ __launch_bounds__(256) void srct_kernel(
    const int* __restrict__ X,
    const float* __restrict__ s_embeds,
    const float* __restrict__ r_embeds,
    const float* __restrict__ p_embeds,
    float* __restrict__ out, int n)
{
    const int g = threadIdx.x >> 4;          // group index within block (0..15)
    const int l = threadIdx.x & 15;          // lane within group
    const long long i0 = ((long long)blockIdx.x * 16 + g) * 2; // first sample
    if (i0 >= n) return;

    // Broadcast loads of the two X rows (16B each, all lanes same address).
    const int4 x0 = *reinterpret_cast<const int4*>(X + 4 * i0);
    const int4 x1 = *reinterpret_cast<const int4*>(X + 4 * (i0 + 1));

    const long long st0 = (long long)x0.x + (long long)x0.w * S_CNT;
    const long long rt0 = (long long)x0.y + (long long)x0.w * R_CNT;
    const long long p0  = x0.z;
    const long long st1 = (long long)x1.x + (long long)x1.w * S_CNT;
    const long long rt1 = (long long)x1.y + (long long)x1.w * R_CNT;
    const long long p1  = x1.z;

    // Issue all 8 gather loads before any arithmetic (MLP).
    const float4 se0 = *reinterpret_cast<const float4*>(s_embeds + st0 * 64 + l * 4);
    const float4 re0 = *reinterpret_cast<const float4*>(r_embeds + rt0 * 64 + l * 4);
    const float4 pl0 = *reinterpret_cast<const float4*>(p_embeds + p0 * 128 + l * 4);
    const float4 ph0 = *reinterpret_cast<const float4*>(p_embeds + p0 * 128 + 64 + l * 4);
    const float4 se1 = *reinterpret_cast<const float4*>(s_embeds + st1 * 64 + l * 4);
    const float4 re1 = *reinterpret_cast<const float4*>(r_embeds + rt1 * 64 + l * 4);
    const float4 pl1 = *reinterpret_cast<const float4*>(p_embeds + p1 * 128 + l * 4);
    const float4 ph1 = *reinterpret_cast<const float4*>(p_embeds + p1 * 128 + 64 + l * 4);

    float a0 = se0.x * pl0.x + se0.y * pl0.y + se0.z * pl0.z + se0.w * pl0.w
             + re0.x * ph0.x + re0.y * ph0.y + re0.z * ph0.z + re0.w * ph0.w;
    float a1 = se1.x * pl1.x + se1.y * pl1.y + se1.z * pl1.z + se1.w * pl1.w
             + re1.x * ph1.x + re1.y * ph1.y + re1.z * ph1.z + re1.w * ph1.w;

    // Reduce across the 16-lane group (xor masks 1,2,4,8 stay within group).
    a0 += __shfl_xor(a0, 1, 64);  a1 += __shfl_xor(a1, 1, 64);
    a0 += __shfl_xor(a0, 2, 64);  a1 += __shfl_xor(a1, 2, 64);
    a0 += __shfl_xor(a0, 4, 64);  a1 += __shfl_xor(a1, 4, 64);
    a0 += __shfl_xor(a0, 8, 64);  a1 += __shfl_xor(a1, 8, 64);

    if (l == 0) {
        float2 o;
        o.x = 1.0f / (1.0f + __expf(-a0));
        o.y = 1.0f / (1.0f + __expf(-a1));
        *reinterpret_cast<float2*>(out + i0) = o;
    }
}

extern "C" void kernel_launch(void* const* d_in, const int* in_sizes, int n_in,
                              void* d_out, int out_size, void* d_ws, size_t ws_size,
                              hipStream_t stream) {
    const int*   X        = (const int*)d_in[0];
    const float* s_embeds = (const float*)d_in[1];
    const float* r_embeds = (const float*)d_in[2];
    const float* p_embeds = (const float*)d_in[3];
    float* out = (float*)d_out;

    const int n = in_sizes[0] / 4;          // N samples (X is N x 4)
    const int blocks = (n + 31) / 32;       // 32 samples per 256-thread block
    srct_kernel<<<blocks, 256, 0, stream>>>(X, s_embeds, r_embeds, p_embeds, out, n);
}